// Round 3
// baseline (407.287 us; speedup 1.0000x reference)
//
#include <hip/hip_runtime.h>
#include <hip/hip_bf16.h>

#define NN 50000
#define EE 800000
#define FF 128
#define HH 128
#define HID2 64
#define TT 8
#define GG 64
#define NBLK ((NN + 255) / 256)   // 196

__device__ inline unsigned short f2bf(float f) {
    union { float f; unsigned u; } v; v.f = f;
    unsigned r = v.u + 0x7fff + ((v.u >> 16) & 1);  // RNE
    return (unsigned short)(r >> 16);
}

// ---------------- K1: in-degree histogram (dst side, excludes self-loop) ----
__global__ void k_hist(const int* __restrict__ dst, int* __restrict__ deg) {
    int e = blockIdx.x * 256 + threadIdx.x;
    if (e < EE) atomicAdd(&deg[dst[e]], 1);
}

// ---------------- K2a: per-block sums of deg -------------------------------
__global__ __launch_bounds__(256) void k_scan1(const int* __restrict__ deg,
                                               int* __restrict__ bsum) {
    __shared__ int red[256];
    int t = threadIdx.x;
    int i = blockIdx.x * 256 + t;
    red[t] = (i < NN) ? deg[i] : 0;
    __syncthreads();
    for (int off = 128; off >= 1; off >>= 1) {
        if (t < off) red[t] += red[t + off];
        __syncthreads();
    }
    if (t == 0) bsum[blockIdx.x] = red[0];
}

// ---------------- K2b: exclusive scan of 196 block sums (one tiny block) ---
__global__ __launch_bounds__(256) void k_scan2(int* __restrict__ bsum) {
    __shared__ int s[256];
    int t = threadIdx.x;
    int v = (t < NBLK) ? bsum[t] : 0;
    s[t] = v;
    __syncthreads();
    for (int off = 1; off < 256; off <<= 1) {
        int a = s[t];
        int b = (t >= off) ? s[t - off] : 0;
        __syncthreads();
        s[t] = a + b;
        __syncthreads();
    }
    if (t < NBLK) bsum[t] = (t == 0) ? 0 : s[t - 1];
}

// ---------------- K2c: in-block scan + offset -> row_ptr, dinv, zero deg ---
__global__ __launch_bounds__(256) void k_scan3(int* __restrict__ deg,
                                               const int* __restrict__ bsum,
                                               int* __restrict__ row_ptr,
                                               float* __restrict__ dinv) {
    __shared__ int s[256];
    int t = threadIdx.x;
    int i = blockIdx.x * 256 + t;
    int v = (i < NN) ? deg[i] : 0;
    s[t] = v;
    __syncthreads();
    for (int off = 1; off < 256; off <<= 1) {
        int a = s[t];
        int b = (t >= off) ? s[t - off] : 0;
        __syncthreads();
        s[t] = a + b;
        __syncthreads();
    }
    int excl = ((t == 0) ? 0 : s[t - 1]) + bsum[blockIdx.x];
    if (i < NN) {
        row_ptr[i] = excl;
        dinv[i] = rsqrtf((float)(v + 1));  // +1 self-loop
        deg[i] = 0;                        // reuse as fill cursor
        if (i == NN - 1) row_ptr[NN] = excl + v;
    }
}

// ---------------- K3: counting-sort fill of CSR col array ------------------
__global__ void k_fill(const int* __restrict__ src, const int* __restrict__ dst,
                       const int* __restrict__ row_ptr, int* __restrict__ cur,
                       int* __restrict__ srcs) {
    int e = blockIdx.x * 256 + threadIdx.x;
    if (e < EE) {
        int d = dst[e];
        int slot = row_ptr[d] + atomicAdd(&cur[d], 1);
        srcs[slot] = src[e];
    }
}

// ---------------- K4: hs = bf16( (x @ W) * dinv[row] )  -------------------
// 64x128 tile, fp32 math, packed-bf16 output (row = 64 uints, 2 feats/uint)
__global__ __launch_bounds__(256) void k_gemm(const float* __restrict__ x,
                                              const float* __restrict__ W,
                                              const float* __restrict__ dinv,
                                              unsigned* __restrict__ hs) {
    __shared__ float xs[64 * 36];
    __shared__ float ws[32 * 132];
    int tid = threadIdx.x;
    int tx = tid & 15, ty = tid >> 4;
    int r0 = blockIdx.x * 64;
    float acc[4][8];
#pragma unroll
    for (int r = 0; r < 4; r++)
#pragma unroll
        for (int c = 0; c < 8; c++) acc[r][c] = 0.f;

    for (int k0 = 0; k0 < 128; k0 += 32) {
        {
            int row = tid >> 2, q = tid & 3;
            int gr = r0 + row;
            float4 a0 = {0, 0, 0, 0}, a1 = {0, 0, 0, 0};
            if (gr < NN) {
                const float4* p = (const float4*)(x + (size_t)gr * 128 + k0 + q * 8);
                a0 = p[0]; a1 = p[1];
            }
            float* dp = &xs[row * 36 + q * 8];
            ((float4*)dp)[0] = a0; ((float4*)dp)[1] = a1;
        }
        {
            int kr = tid >> 3, q = tid & 7;
            const float4* p = (const float4*)(W + (size_t)(k0 + kr) * 128 + q * 16);
            float4 b0 = p[0], b1 = p[1], b2 = p[2], b3 = p[3];
            float* dp = &ws[kr * 132 + q * 16];
            ((float4*)dp)[0] = b0; ((float4*)dp)[1] = b1;
            ((float4*)dp)[2] = b2; ((float4*)dp)[3] = b3;
        }
        __syncthreads();
#pragma unroll
        for (int kk = 0; kk < 32; kk++) {
            float a[4];
#pragma unroll
            for (int r = 0; r < 4; r++) a[r] = xs[(ty * 4 + r) * 36 + kk];
            float4 b0 = *(const float4*)&ws[kk * 132 + tx * 8];
            float4 b1 = *(const float4*)&ws[kk * 132 + tx * 8 + 4];
            float bv[8] = {b0.x, b0.y, b0.z, b0.w, b1.x, b1.y, b1.z, b1.w};
#pragma unroll
            for (int r = 0; r < 4; r++)
#pragma unroll
                for (int c = 0; c < 8; c++)
                    acc[r][c] = fmaf(a[r], bv[c], acc[r][c]);
        }
        __syncthreads();
    }
#pragma unroll
    for (int r = 0; r < 4; r++) {
        int gr = r0 + ty * 4 + r;
        if (gr < NN) {
            float di = dinv[gr];
            unsigned p0 = f2bf(acc[r][0] * di) | ((unsigned)f2bf(acc[r][1] * di) << 16);
            unsigned p1 = f2bf(acc[r][2] * di) | ((unsigned)f2bf(acc[r][3] * di) << 16);
            unsigned p2 = f2bf(acc[r][4] * di) | ((unsigned)f2bf(acc[r][5] * di) << 16);
            unsigned p3 = f2bf(acc[r][6] * di) | ((unsigned)f2bf(acc[r][7] * di) << 16);
            uint4 o = {p0, p1, p2, p3};
            *(uint4*)(hs + (size_t)gr * 64 + tx * 4) = o;
        }
    }
}

// ---------------- K5: gather-aggregate + bias + relu + fused group pool ----
// wave per node; lane holds features (2*lane, 2*lane+1)
__global__ __launch_bounds__(256) void k_aggr(const unsigned* __restrict__ hs,
                                              const int* __restrict__ row_ptr,
                                              const int* __restrict__ srcs,
                                              const float* __restrict__ dinv,
                                              const float* __restrict__ bias,
                                              const int* __restrict__ batch,
                                              float* __restrict__ gsum) {
    int wave = threadIdx.x >> 6;
    int lane = threadIdx.x & 63;
    int i = blockIdx.x * 4 + wave;  // grid = NN/4 exactly
    float di = dinv[i];
    unsigned su = hs[(size_t)i * 64 + lane];  // self-loop (pre-scaled row)
    float ax = __uint_as_float(su << 16);
    float ay = __uint_as_float(su & 0xffff0000u);
    int e0 = row_ptr[i], e1 = row_ptr[i + 1];
    int e = e0;
    for (; e + 1 < e1; e += 2) {
        int s0 = srcs[e], s1 = srcs[e + 1];
        unsigned u0 = hs[(size_t)s0 * 64 + lane];
        unsigned u1 = hs[(size_t)s1 * 64 + lane];
        ax += __uint_as_float(u0 << 16);
        ay += __uint_as_float(u0 & 0xffff0000u);
        ax += __uint_as_float(u1 << 16);
        ay += __uint_as_float(u1 & 0xffff0000u);
    }
    if (e < e1) {
        unsigned u0 = hs[(size_t)srcs[e] * 64 + lane];
        ax += __uint_as_float(u0 << 16);
        ay += __uint_as_float(u0 & 0xffff0000u);
    }
    float2 bb = ((const float2*)bias)[lane];
    float rx = fmaxf(fmaf(ax, di, bb.x), 0.f);
    float ry = fmaxf(fmaf(ay, di, bb.y), 0.f);
    int g = batch[i];
    atomicAdd(&gsum[g * 128 + lane * 2], rx);
    atomicAdd(&gsum[g * 128 + lane * 2 + 1], ry);
}

__device__ inline int lbound(const int* __restrict__ a, int n, int key) {
    int lo = 0, hi = n;
    while (lo < hi) {
        int mid = (lo + hi) >> 1;
        if (a[mid] < key) lo = mid + 1;
        else hi = mid;
    }
    return lo;
}

// ---------------- K7: head (mean, fc1 + relu, actor softmax, critic) -------
__global__ __launch_bounds__(64) void k_head(const float* __restrict__ gsum,
                                             const int* __restrict__ batch,
                                             const float* __restrict__ fc1_w,
                                             const float* __restrict__ fc1_b,
                                             const float* __restrict__ actor_w,
                                             const float* __restrict__ actor_b,
                                             const float* __restrict__ critic_w,
                                             const float* __restrict__ critic_b,
                                             float* __restrict__ out) {
    __shared__ float gs[128];
    __shared__ float zs[64];
    __shared__ float ls[8], es[8];
    int g = blockIdx.x, t = threadIdx.x;
    int lo = lbound(batch, NN, g), hi = lbound(batch, NN, g + 1);
    float invc = 1.f / fmaxf((float)(hi - lo), 1.f);
    gs[t] = gsum[g * 128 + t] * invc;
    gs[t + 64] = gsum[g * 128 + 64 + t] * invc;
    __syncthreads();
    float z = fc1_b[t];
    for (int k = 0; k < 128; k++) z = fmaf(gs[k], fc1_w[k * 64 + t], z);
    zs[t] = fmaxf(z, 0.f);
    __syncthreads();
    if (t < 8) {
        float l = actor_b[t];
        for (int k = 0; k < 64; k++) l = fmaf(zs[k], actor_w[k * 8 + t], l);
        ls[t] = l;
    }
    __syncthreads();
    if (t < 8) {
        float m = ls[0];
#pragma unroll
        for (int j = 1; j < 8; j++) m = fmaxf(m, ls[j]);
        es[t] = expf(ls[t] - m);
    }
    __syncthreads();
    if (t < 8) {
        float ssum = 0.f;
#pragma unroll
        for (int j = 0; j < 8; j++) ssum += es[j];
        out[g * 8 + t] = es[t] / ssum;
    }
    if (t == 32) {
        float v = critic_b[0];
        for (int k = 0; k < 64; k++) v = fmaf(zs[k], critic_w[k], v);
        out[GG * TT + g] = v;
    }
}

extern "C" void kernel_launch(void* const* d_in, const int* in_sizes, int n_in,
                              void* d_out, int out_size, void* d_ws, size_t ws_size,
                              hipStream_t stream) {
    const float* x        = (const float*)d_in[0];
    const int*   ei       = (const int*)d_in[1];
    const int*   batch    = (const int*)d_in[2];
    const float* W        = (const float*)d_in[3];
    const float* b        = (const float*)d_in[4];
    const float* fc1_w    = (const float*)d_in[5];
    const float* fc1_b    = (const float*)d_in[6];
    const float* actor_w  = (const float*)d_in[7];
    const float* actor_b  = (const float*)d_in[8];
    const float* critic_w = (const float*)d_in[9];
    const float* critic_b = (const float*)d_in[10];
    float* out = (float*)d_out;

    char* ws = (char*)d_ws;
    size_t off = 0;
    unsigned* hs     = (unsigned*)(ws + off); off += (size_t)NN * 64 * 4;  // 12.8 MB packed bf16
    float* dinv      = (float*)(ws + off);    off += (size_t)NN * 4;
    int*   deg       = (int*)(ws + off);      off += (size_t)NN * 4;
    int*   row_ptr   = (int*)(ws + off);      off += (size_t)(NN + 1) * 4 + 12;
    int*   srcs      = (int*)(ws + off);      off += (size_t)EE * 4;       // 3.2 MB
    float* gsum      = (float*)(ws + off);    off += (size_t)GG * HH * 4;
    int*   bsum      = (int*)(ws + off);      off += (size_t)256 * 4;

    hipMemsetAsync(deg, 0, (size_t)NN * 4, stream);
    hipMemsetAsync(gsum, 0, (size_t)GG * HH * 4, stream);

    const int* src = ei;        // edge_index[0]
    const int* dst = ei + EE;   // edge_index[1]

    k_hist<<<EE / 256, 256, 0, stream>>>(dst, deg);
    k_scan1<<<NBLK, 256, 0, stream>>>(deg, bsum);
    k_scan2<<<1, 256, 0, stream>>>(bsum);
    k_scan3<<<NBLK, 256, 0, stream>>>(deg, bsum, row_ptr, dinv);
    k_fill<<<EE / 256, 256, 0, stream>>>(src, dst, row_ptr, deg, srcs);
    k_gemm<<<(NN + 63) / 64, 256, 0, stream>>>(x, W, dinv, hs);
    k_aggr<<<NN / 4, 256, 0, stream>>>(hs, row_ptr, srcs, dinv, b, batch, gsum);
    k_head<<<GG, 64, 0, stream>>>(gsum, batch, fc1_w, fc1_b, actor_w, actor_b,
                                  critic_w, critic_b, out);
}

// Round 4
// 267.102 us; speedup vs baseline: 1.5248x; 1.5248x over previous
//
#include <hip/hip_runtime.h>
#include <hip/hip_bf16.h>

#define NN 50000
#define EE 800000
#define FF 128
#define HH 128
#define HID2 64
#define TT 8
#define GG 64
#define NBLK ((NN + 255) / 256)   // 196

__device__ inline unsigned short f2bf(float f) {
    union { float f; unsigned u; } v; v.f = f;
    unsigned r = v.u + 0x7fff + ((v.u >> 16) & 1);  // RNE
    return (unsigned short)(r >> 16);
}

// ---------------- K1: in-degree histogram (dst side, excludes self-loop) ----
__global__ void k_hist(const int* __restrict__ dst, int* __restrict__ deg) {
    int e = blockIdx.x * 256 + threadIdx.x;
    if (e < EE) atomicAdd(&deg[dst[e]], 1);
}

// ---------------- K2a: per-block sums of deg -------------------------------
__global__ __launch_bounds__(256) void k_scan1(const int* __restrict__ deg,
                                               int* __restrict__ bsum) {
    __shared__ int red[256];
    int t = threadIdx.x;
    int i = blockIdx.x * 256 + t;
    red[t] = (i < NN) ? deg[i] : 0;
    __syncthreads();
    for (int off = 128; off >= 1; off >>= 1) {
        if (t < off) red[t] += red[t + off];
        __syncthreads();
    }
    if (t == 0) bsum[blockIdx.x] = red[0];
}

// ---------------- K2b: exclusive scan of 196 block sums (one tiny block) ---
__global__ __launch_bounds__(256) void k_scan2(int* __restrict__ bsum) {
    __shared__ int s[256];
    int t = threadIdx.x;
    int v = (t < NBLK) ? bsum[t] : 0;
    s[t] = v;
    __syncthreads();
    for (int off = 1; off < 256; off <<= 1) {
        int a = s[t];
        int b = (t >= off) ? s[t - off] : 0;
        __syncthreads();
        s[t] = a + b;
        __syncthreads();
    }
    if (t < NBLK) bsum[t] = (t == 0) ? 0 : s[t - 1];
}

// ---------------- K2c: in-block scan + offset -> row_ptr, dinv, zero deg ---
__global__ __launch_bounds__(256) void k_scan3(int* __restrict__ deg,
                                               const int* __restrict__ bsum,
                                               int* __restrict__ row_ptr,
                                               float* __restrict__ dinv) {
    __shared__ int s[256];
    int t = threadIdx.x;
    int i = blockIdx.x * 256 + t;
    int v = (i < NN) ? deg[i] : 0;
    s[t] = v;
    __syncthreads();
    for (int off = 1; off < 256; off <<= 1) {
        int a = s[t];
        int b = (t >= off) ? s[t - off] : 0;
        __syncthreads();
        s[t] = a + b;
        __syncthreads();
    }
    int excl = ((t == 0) ? 0 : s[t - 1]) + bsum[blockIdx.x];
    if (i < NN) {
        row_ptr[i] = excl;
        dinv[i] = rsqrtf((float)(v + 1));  // +1 self-loop
        deg[i] = 0;                        // reuse as fill cursor
        if (i == NN - 1) row_ptr[NN] = excl + v;
    }
}

// ---------------- K3: counting-sort fill of CSR col array ------------------
__global__ void k_fill(const int* __restrict__ src, const int* __restrict__ dst,
                       const int* __restrict__ row_ptr, int* __restrict__ cur,
                       int* __restrict__ srcs) {
    int e = blockIdx.x * 256 + threadIdx.x;
    if (e < EE) {
        int d = dst[e];
        int slot = row_ptr[d] + atomicAdd(&cur[d], 1);
        srcs[slot] = src[e];
    }
}

// ---------------- K4: hs = bf16( (x @ W) * dinv[row] )  -------------------
// 64x128 tile, fp32 math, packed-bf16 output (row = 64 uints, 2 feats/uint)
__global__ __launch_bounds__(256) void k_gemm(const float* __restrict__ x,
                                              const float* __restrict__ W,
                                              const float* __restrict__ dinv,
                                              unsigned* __restrict__ hs) {
    __shared__ float xs[64 * 36];
    __shared__ float ws[32 * 132];
    int tid = threadIdx.x;
    int tx = tid & 15, ty = tid >> 4;
    int r0 = blockIdx.x * 64;
    float acc[4][8];
#pragma unroll
    for (int r = 0; r < 4; r++)
#pragma unroll
        for (int c = 0; c < 8; c++) acc[r][c] = 0.f;

    for (int k0 = 0; k0 < 128; k0 += 32) {
        {
            int row = tid >> 2, q = tid & 3;
            int gr = r0 + row;
            float4 a0 = {0, 0, 0, 0}, a1 = {0, 0, 0, 0};
            if (gr < NN) {
                const float4* p = (const float4*)(x + (size_t)gr * 128 + k0 + q * 8);
                a0 = p[0]; a1 = p[1];
            }
            float* dp = &xs[row * 36 + q * 8];
            ((float4*)dp)[0] = a0; ((float4*)dp)[1] = a1;
        }
        {
            int kr = tid >> 3, q = tid & 7;
            const float4* p = (const float4*)(W + (size_t)(k0 + kr) * 128 + q * 16);
            float4 b0 = p[0], b1 = p[1], b2 = p[2], b3 = p[3];
            float* dp = &ws[kr * 132 + q * 16];
            ((float4*)dp)[0] = b0; ((float4*)dp)[1] = b1;
            ((float4*)dp)[2] = b2; ((float4*)dp)[3] = b3;
        }
        __syncthreads();
#pragma unroll
        for (int kk = 0; kk < 32; kk++) {
            float a[4];
#pragma unroll
            for (int r = 0; r < 4; r++) a[r] = xs[(ty * 4 + r) * 36 + kk];
            float4 b0 = *(const float4*)&ws[kk * 132 + tx * 8];
            float4 b1 = *(const float4*)&ws[kk * 132 + tx * 8 + 4];
            float bv[8] = {b0.x, b0.y, b0.z, b0.w, b1.x, b1.y, b1.z, b1.w};
#pragma unroll
            for (int r = 0; r < 4; r++)
#pragma unroll
                for (int c = 0; c < 8; c++)
                    acc[r][c] = fmaf(a[r], bv[c], acc[r][c]);
        }
        __syncthreads();
    }
#pragma unroll
    for (int r = 0; r < 4; r++) {
        int gr = r0 + ty * 4 + r;
        if (gr < NN) {
            float di = dinv[gr];
            unsigned p0 = f2bf(acc[r][0] * di) | ((unsigned)f2bf(acc[r][1] * di) << 16);
            unsigned p1 = f2bf(acc[r][2] * di) | ((unsigned)f2bf(acc[r][3] * di) << 16);
            unsigned p2 = f2bf(acc[r][4] * di) | ((unsigned)f2bf(acc[r][5] * di) << 16);
            unsigned p3 = f2bf(acc[r][6] * di) | ((unsigned)f2bf(acc[r][7] * di) << 16);
            uint4 o = {p0, p1, p2, p3};
            *(uint4*)(hs + (size_t)gr * 64 + tx * 4) = o;
        }
    }
}

// ---------------- K5: gather-aggregate + bias + relu -> h2 (fp32) ----------
// quarter-wave (16 lanes) per node; lane holds feats [sub*8, sub*8+8)
// via one uint4 (16B) load per row. 4 nodes/wave, 16 nodes/block.
__global__ __launch_bounds__(256) void k_aggr(const uint4* __restrict__ hs4,
                                              const int* __restrict__ row_ptr,
                                              const int* __restrict__ srcs,
                                              const float* __restrict__ dinv,
                                              const float* __restrict__ bias,
                                              float* __restrict__ h2) {
    int tid = threadIdx.x;
    int wave = tid >> 6, lane = tid & 63;
    int q = lane >> 4, sub = lane & 15;
    int i = blockIdx.x * 16 + wave * 4 + q;   // grid = NN/16 exactly
    float di = dinv[i];
    uint4 su = hs4[(size_t)i * 16 + sub];     // self row (pre-scaled by dinv[i])
    float a0 = __uint_as_float(su.x << 16);
    float a1 = __uint_as_float(su.x & 0xffff0000u);
    float a2 = __uint_as_float(su.y << 16);
    float a3 = __uint_as_float(su.y & 0xffff0000u);
    float a4 = __uint_as_float(su.z << 16);
    float a5 = __uint_as_float(su.z & 0xffff0000u);
    float a6 = __uint_as_float(su.w << 16);
    float a7 = __uint_as_float(su.w & 0xffff0000u);
    int e = row_ptr[i], e1 = row_ptr[i + 1];
    for (; e + 1 < e1; e += 2) {
        int s0 = srcs[e], s1 = srcs[e + 1];
        uint4 u0 = hs4[(size_t)s0 * 16 + sub];
        uint4 u1 = hs4[(size_t)s1 * 16 + sub];
        a0 += __uint_as_float(u0.x << 16);
        a1 += __uint_as_float(u0.x & 0xffff0000u);
        a2 += __uint_as_float(u0.y << 16);
        a3 += __uint_as_float(u0.y & 0xffff0000u);
        a4 += __uint_as_float(u0.z << 16);
        a5 += __uint_as_float(u0.z & 0xffff0000u);
        a6 += __uint_as_float(u0.w << 16);
        a7 += __uint_as_float(u0.w & 0xffff0000u);
        a0 += __uint_as_float(u1.x << 16);
        a1 += __uint_as_float(u1.x & 0xffff0000u);
        a2 += __uint_as_float(u1.y << 16);
        a3 += __uint_as_float(u1.y & 0xffff0000u);
        a4 += __uint_as_float(u1.z << 16);
        a5 += __uint_as_float(u1.z & 0xffff0000u);
        a6 += __uint_as_float(u1.w << 16);
        a7 += __uint_as_float(u1.w & 0xffff0000u);
    }
    if (e < e1) {
        uint4 u0 = hs4[(size_t)srcs[e] * 16 + sub];
        a0 += __uint_as_float(u0.x << 16);
        a1 += __uint_as_float(u0.x & 0xffff0000u);
        a2 += __uint_as_float(u0.y << 16);
        a3 += __uint_as_float(u0.y & 0xffff0000u);
        a4 += __uint_as_float(u0.z << 16);
        a5 += __uint_as_float(u0.z & 0xffff0000u);
        a6 += __uint_as_float(u0.w << 16);
        a7 += __uint_as_float(u0.w & 0xffff0000u);
    }
    const float4* b4 = (const float4*)(bias + sub * 8);
    float4 bb0 = b4[0], bb1 = b4[1];
    float4 r0, r1;
    r0.x = fmaxf(fmaf(a0, di, bb0.x), 0.f);
    r0.y = fmaxf(fmaf(a1, di, bb0.y), 0.f);
    r0.z = fmaxf(fmaf(a2, di, bb0.z), 0.f);
    r0.w = fmaxf(fmaf(a3, di, bb0.w), 0.f);
    r1.x = fmaxf(fmaf(a4, di, bb1.x), 0.f);
    r1.y = fmaxf(fmaf(a5, di, bb1.y), 0.f);
    r1.z = fmaxf(fmaf(a6, di, bb1.z), 0.f);
    r1.w = fmaxf(fmaf(a7, di, bb1.w), 0.f);
    float4* o = (float4*)(h2 + (size_t)i * 128 + sub * 8);
    o[0] = r0; o[1] = r1;
}

__device__ inline int lbound(const int* __restrict__ a, int n, int key) {
    int lo = 0, hi = n;
    while (lo < hi) {
        int mid = (lo + hi) >> 1;
        if (a[mid] < key) lo = mid + 1;
        else hi = mid;
    }
    return lo;
}

// ---------------- K6: group mean-pool partial sums (16 chunks/group) -------
__global__ __launch_bounds__(128) void k_pool(const float* __restrict__ h2,
                                              const int* __restrict__ batch,
                                              float* __restrict__ gsum) {
    int g = blockIdx.x >> 4, chunk = blockIdx.x & 15;
    int lo = lbound(batch, NN, g);
    int hi = lbound(batch, NN, g + 1);
    int cnt = hi - lo;
    int per = (cnt + 15) >> 4;
    int rs = lo + chunk * per;
    int re = rs + per;
    if (re > hi) re = hi;
    if (rs >= re) return;
    float s = 0.f;
    int f = threadIdx.x;
    for (int r = rs; r < re; ++r) s += h2[(size_t)r * 128 + f];
    atomicAdd(&gsum[g * 128 + f], s);
}

// ---------------- K7: head (mean, fc1 + relu, actor softmax, critic) -------
__global__ __launch_bounds__(64) void k_head(const float* __restrict__ gsum,
                                             const int* __restrict__ batch,
                                             const float* __restrict__ fc1_w,
                                             const float* __restrict__ fc1_b,
                                             const float* __restrict__ actor_w,
                                             const float* __restrict__ actor_b,
                                             const float* __restrict__ critic_w,
                                             const float* __restrict__ critic_b,
                                             float* __restrict__ out) {
    __shared__ float gs[128];
    __shared__ float zs[64];
    __shared__ float ls[8], es[8];
    int g = blockIdx.x, t = threadIdx.x;
    int lo = lbound(batch, NN, g), hi = lbound(batch, NN, g + 1);
    float invc = 1.f / fmaxf((float)(hi - lo), 1.f);
    gs[t] = gsum[g * 128 + t] * invc;
    gs[t + 64] = gsum[g * 128 + 64 + t] * invc;
    __syncthreads();
    float z = fc1_b[t];
    for (int k = 0; k < 128; k++) z = fmaf(gs[k], fc1_w[k * 64 + t], z);
    zs[t] = fmaxf(z, 0.f);
    __syncthreads();
    if (t < 8) {
        float l = actor_b[t];
        for (int k = 0; k < 64; k++) l = fmaf(zs[k], actor_w[k * 8 + t], l);
        ls[t] = l;
    }
    __syncthreads();
    if (t < 8) {
        float m = ls[0];
#pragma unroll
        for (int j = 1; j < 8; j++) m = fmaxf(m, ls[j]);
        es[t] = expf(ls[t] - m);
    }
    __syncthreads();
    if (t < 8) {
        float ssum = 0.f;
#pragma unroll
        for (int j = 0; j < 8; j++) ssum += es[j];
        out[g * 8 + t] = es[t] / ssum;
    }
    if (t == 32) {
        float v = critic_b[0];
        for (int k = 0; k < 64; k++) v = fmaf(zs[k], critic_w[k], v);
        out[GG * TT + g] = v;
    }
}

extern "C" void kernel_launch(void* const* d_in, const int* in_sizes, int n_in,
                              void* d_out, int out_size, void* d_ws, size_t ws_size,
                              hipStream_t stream) {
    const float* x        = (const float*)d_in[0];
    const int*   ei       = (const int*)d_in[1];
    const int*   batch    = (const int*)d_in[2];
    const float* W        = (const float*)d_in[3];
    const float* b        = (const float*)d_in[4];
    const float* fc1_w    = (const float*)d_in[5];
    const float* fc1_b    = (const float*)d_in[6];
    const float* actor_w  = (const float*)d_in[7];
    const float* actor_b  = (const float*)d_in[8];
    const float* critic_w = (const float*)d_in[9];
    const float* critic_b = (const float*)d_in[10];
    float* out = (float*)d_out;

    char* ws = (char*)d_ws;
    size_t off = 0;
    unsigned* hs     = (unsigned*)(ws + off); off += (size_t)NN * 64 * 4;  // 12.8 MB packed bf16
    float* h2        = (float*)(ws + off);    off += (size_t)NN * HH * 4;  // 25.6 MB
    float* dinv      = (float*)(ws + off);    off += (size_t)NN * 4;
    int*   deg       = (int*)(ws + off);      off += (size_t)NN * 4;
    int*   row_ptr   = (int*)(ws + off);      off += (size_t)(NN + 1) * 4 + 12;
    int*   srcs      = (int*)(ws + off);      off += (size_t)EE * 4;       // 3.2 MB
    float* gsum      = (float*)(ws + off);    off += (size_t)GG * HH * 4;
    int*   bsum      = (int*)(ws + off);      off += (size_t)256 * 4;

    hipMemsetAsync(deg, 0, (size_t)NN * 4, stream);
    hipMemsetAsync(gsum, 0, (size_t)GG * HH * 4, stream);

    const int* src = ei;        // edge_index[0]
    const int* dst = ei + EE;   // edge_index[1]

    k_hist<<<EE / 256, 256, 0, stream>>>(dst, deg);
    k_scan1<<<NBLK, 256, 0, stream>>>(deg, bsum);
    k_scan2<<<1, 256, 0, stream>>>(bsum);
    k_scan3<<<NBLK, 256, 0, stream>>>(deg, bsum, row_ptr, dinv);
    k_fill<<<EE / 256, 256, 0, stream>>>(src, dst, row_ptr, deg, srcs);
    k_gemm<<<(NN + 63) / 64, 256, 0, stream>>>(x, W, dinv, hs);
    k_aggr<<<NN / 16, 256, 0, stream>>>((const uint4*)hs, row_ptr, srcs, dinv, b, h2);
    k_pool<<<GG * 16, 128, 0, stream>>>(h2, batch, gsum);
    k_head<<<GG, 64, 0, stream>>>(gsum, batch, fc1_w, fc1_b, actor_w, actor_b,
                                  critic_w, critic_b, out);
}

// Round 5
// 227.078 us; speedup vs baseline: 1.7936x; 1.1763x over previous
//
#include <hip/hip_runtime.h>
#include <hip/hip_bf16.h>

#define NN 50000
#define EE 800000
#define FF 128
#define HH 128
#define HID2 64
#define TT 8
#define GG 64
#define NB 196     // buckets of 256 dst nodes (NN < 196*256 = 50176; NN < 2^16)
#define NSB 64     // scatter blocks
#define EPB (EE / NSB)  // 12500 edges per scatter block

__device__ inline unsigned short f2bf(float f) {
    union { float f; unsigned u; } v; v.f = f;
    unsigned r = v.u + 0x7fff + ((v.u >> 16) & 1);  // RNE
    return (unsigned short)(r >> 16);
}

// ---- KB1: per-(scatter-block, bucket) edge counts (LDS hist, no glb atomics)
__global__ __launch_bounds__(1024) void kb1(const int* __restrict__ dst,
                                            int* __restrict__ table) {
    __shared__ int cnt[NB];
    int t = threadIdx.x, blk = blockIdx.x;
    for (int i = t; i < NB; i += 1024) cnt[i] = 0;
    __syncthreads();
    int e0 = blk * EPB;
    for (int e = e0 + t; e < e0 + EPB; e += 1024)
        atomicAdd(&cnt[dst[e] >> 8], 1);
    __syncthreads();
    for (int i = t; i < NB; i += 1024) table[blk * NB + i] = cnt[i];
}

// ---- KB2: exact scan of table -> scatter offsets; bucket bases ------------
__global__ __launch_bounds__(256) void kb2(int* __restrict__ table,
                                           int* __restrict__ bbase) {
    __shared__ int s[256];
    int b = threadIdx.x;
    int tot = 0;
    if (b < NB)
        for (int blk = 0; blk < NSB; blk++) tot += table[blk * NB + b];
    s[b] = (b < NB) ? tot : 0;
    __syncthreads();
    for (int off = 1; off < 256; off <<= 1) {
        int a = s[b];
        int w = (b >= off) ? s[b - off] : 0;
        __syncthreads();
        s[b] = a + w;
        __syncthreads();
    }
    int base = (b == 0) ? 0 : s[b - 1];
    if (b < NB) {
        bbase[b] = base;
        int run = base;
        for (int blk = 0; blk < NSB; blk++) {
            int v = table[blk * NB + b];
            table[blk * NB + b] = run;
            run += v;
        }
    }
    if (b == 0) bbase[NB] = EE;
}

// ---- KB3: scatter edges into bucket order (packed dst<<16|src) ------------
__global__ __launch_bounds__(1024) void kb3(const int* __restrict__ src,
                                            const int* __restrict__ dst,
                                            const int* __restrict__ table,
                                            unsigned* __restrict__ etmp) {
    __shared__ int ofs[NB];
    __shared__ int cur[NB];
    int t = threadIdx.x, blk = blockIdx.x;
    for (int i = t; i < NB; i += 1024) { ofs[i] = table[blk * NB + i]; cur[i] = 0; }
    __syncthreads();
    int e0 = blk * EPB;
    for (int e = e0 + t; e < e0 + EPB; e += 1024) {
        int d = dst[e];
        int b = d >> 8;
        int r = atomicAdd(&cur[b], 1);
        etmp[ofs[b] + r] = ((unsigned)d << 16) | (unsigned)src[e];
    }
}

// ---- KDEG: per-bucket LDS degree histogram -> deg (replaces k_hist) -------
__global__ __launch_bounds__(256) void kdeg(const unsigned* __restrict__ etmp,
                                            const int* __restrict__ bbase,
                                            int* __restrict__ deg) {
    __shared__ int cnt[256];
    int t = threadIdx.x, b = blockIdx.x;
    cnt[t] = 0;
    __syncthreads();
    int e0 = bbase[b], e1 = bbase[b + 1];
    for (int e = e0 + t; e < e1; e += 256)
        atomicAdd(&cnt[(etmp[e] >> 16) & 255], 1);
    __syncthreads();
    int node = b * 256 + t;
    if (node < NN) deg[node] = cnt[t];
}

// ---- K_ROWPTR: local scan + bbase offset -> row_ptr, dinv -----------------
// row_ptr[b*256] == bbase[b], so no inter-block scan needed.
__global__ __launch_bounds__(256) void k_rowptr(const int* __restrict__ deg,
                                                const int* __restrict__ bbase,
                                                int* __restrict__ row_ptr,
                                                float* __restrict__ dinv) {
    __shared__ int s[256];
    int t = threadIdx.x, b = blockIdx.x;
    int i = b * 256 + t;
    int v = (i < NN) ? deg[i] : 0;
    s[t] = v;
    __syncthreads();
    for (int off = 1; off < 256; off <<= 1) {
        int a = s[t];
        int w = (t >= off) ? s[t - off] : 0;
        __syncthreads();
        s[t] = a + w;
        __syncthreads();
    }
    int excl = ((t == 0) ? 0 : s[t - 1]) + bbase[b];
    if (i < NN) {
        row_ptr[i] = excl;
        dinv[i] = rsqrtf((float)(v + 1));  // +1 self-loop
        if (i == NN - 1) row_ptr[NN] = excl + v;
    }
}

// ---- K_FILLL: per-bucket CSR fill with LDS cursors (local writes) ---------
__global__ __launch_bounds__(256) void k_filll(const unsigned* __restrict__ etmp,
                                               const int* __restrict__ bbase,
                                               const int* __restrict__ row_ptr,
                                               int* __restrict__ srcs) {
    __shared__ int cur[256];
    int t = threadIdx.x, b = blockIdx.x;
    int node = b * 256 + t;
    cur[t] = row_ptr[(node < NN) ? node : NN];
    __syncthreads();
    int e0 = bbase[b], e1 = bbase[b + 1];
    for (int e = e0 + t; e < e1; e += 256) {
        unsigned u = etmp[e];
        int slot = atomicAdd(&cur[(u >> 16) & 255], 1);
        srcs[slot] = (int)(u & 0xffffu);
    }
}

// ---------------- K4: hs = bf16( (x @ W) * dinv[row] )  --------------------
__global__ __launch_bounds__(256) void k_gemm(const float* __restrict__ x,
                                              const float* __restrict__ W,
                                              const float* __restrict__ dinv,
                                              unsigned* __restrict__ hs) {
    __shared__ float xs[64 * 36];
    __shared__ float ws[32 * 132];
    int tid = threadIdx.x;
    int tx = tid & 15, ty = tid >> 4;
    int r0 = blockIdx.x * 64;
    float acc[4][8];
#pragma unroll
    for (int r = 0; r < 4; r++)
#pragma unroll
        for (int c = 0; c < 8; c++) acc[r][c] = 0.f;

    for (int k0 = 0; k0 < 128; k0 += 32) {
        {
            int row = tid >> 2, q = tid & 3;
            int gr = r0 + row;
            float4 a0 = {0, 0, 0, 0}, a1 = {0, 0, 0, 0};
            if (gr < NN) {
                const float4* p = (const float4*)(x + (size_t)gr * 128 + k0 + q * 8);
                a0 = p[0]; a1 = p[1];
            }
            float* dp = &xs[row * 36 + q * 8];
            ((float4*)dp)[0] = a0; ((float4*)dp)[1] = a1;
        }
        {
            int kr = tid >> 3, q = tid & 7;
            const float4* p = (const float4*)(W + (size_t)(k0 + kr) * 128 + q * 16);
            float4 b0 = p[0], b1 = p[1], b2 = p[2], b3 = p[3];
            float* dp = &ws[kr * 132 + q * 16];
            ((float4*)dp)[0] = b0; ((float4*)dp)[1] = b1;
            ((float4*)dp)[2] = b2; ((float4*)dp)[3] = b3;
        }
        __syncthreads();
#pragma unroll
        for (int kk = 0; kk < 32; kk++) {
            float a[4];
#pragma unroll
            for (int r = 0; r < 4; r++) a[r] = xs[(ty * 4 + r) * 36 + kk];
            float4 b0 = *(const float4*)&ws[kk * 132 + tx * 8];
            float4 b1 = *(const float4*)&ws[kk * 132 + tx * 8 + 4];
            float bv[8] = {b0.x, b0.y, b0.z, b0.w, b1.x, b1.y, b1.z, b1.w};
#pragma unroll
            for (int r = 0; r < 4; r++)
#pragma unroll
                for (int c = 0; c < 8; c++)
                    acc[r][c] = fmaf(a[r], bv[c], acc[r][c]);
        }
        __syncthreads();
    }
#pragma unroll
    for (int r = 0; r < 4; r++) {
        int gr = r0 + ty * 4 + r;
        if (gr < NN) {
            float di = dinv[gr];
            unsigned p0 = f2bf(acc[r][0] * di) | ((unsigned)f2bf(acc[r][1] * di) << 16);
            unsigned p1 = f2bf(acc[r][2] * di) | ((unsigned)f2bf(acc[r][3] * di) << 16);
            unsigned p2 = f2bf(acc[r][4] * di) | ((unsigned)f2bf(acc[r][5] * di) << 16);
            unsigned p3 = f2bf(acc[r][6] * di) | ((unsigned)f2bf(acc[r][7] * di) << 16);
            uint4 o = {p0, p1, p2, p3};
            *(uint4*)(hs + (size_t)gr * 64 + tx * 4) = o;
        }
    }
}

// ---------------- K5: gather-aggregate + bias + relu -> h2 (fp32) ----------
__global__ __launch_bounds__(256) void k_aggr(const uint4* __restrict__ hs4,
                                              const int* __restrict__ row_ptr,
                                              const int* __restrict__ srcs,
                                              const float* __restrict__ dinv,
                                              const float* __restrict__ bias,
                                              float* __restrict__ h2) {
    int tid = threadIdx.x;
    int wave = tid >> 6, lane = tid & 63;
    int q = lane >> 4, sub = lane & 15;
    int i = blockIdx.x * 16 + wave * 4 + q;   // grid = NN/16 exactly
    float di = dinv[i];
    uint4 su = hs4[(size_t)i * 16 + sub];
    float a0 = __uint_as_float(su.x << 16);
    float a1 = __uint_as_float(su.x & 0xffff0000u);
    float a2 = __uint_as_float(su.y << 16);
    float a3 = __uint_as_float(su.y & 0xffff0000u);
    float a4 = __uint_as_float(su.z << 16);
    float a5 = __uint_as_float(su.z & 0xffff0000u);
    float a6 = __uint_as_float(su.w << 16);
    float a7 = __uint_as_float(su.w & 0xffff0000u);
    int e = row_ptr[i], e1 = row_ptr[i + 1];
    for (; e + 1 < e1; e += 2) {
        int s0 = srcs[e], s1 = srcs[e + 1];
        uint4 u0 = hs4[(size_t)s0 * 16 + sub];
        uint4 u1 = hs4[(size_t)s1 * 16 + sub];
        a0 += __uint_as_float(u0.x << 16);
        a1 += __uint_as_float(u0.x & 0xffff0000u);
        a2 += __uint_as_float(u0.y << 16);
        a3 += __uint_as_float(u0.y & 0xffff0000u);
        a4 += __uint_as_float(u0.z << 16);
        a5 += __uint_as_float(u0.z & 0xffff0000u);
        a6 += __uint_as_float(u0.w << 16);
        a7 += __uint_as_float(u0.w & 0xffff0000u);
        a0 += __uint_as_float(u1.x << 16);
        a1 += __uint_as_float(u1.x & 0xffff0000u);
        a2 += __uint_as_float(u1.y << 16);
        a3 += __uint_as_float(u1.y & 0xffff0000u);
        a4 += __uint_as_float(u1.z << 16);
        a5 += __uint_as_float(u1.z & 0xffff0000u);
        a6 += __uint_as_float(u1.w << 16);
        a7 += __uint_as_float(u1.w & 0xffff0000u);
    }
    if (e < e1) {
        uint4 u0 = hs4[(size_t)srcs[e] * 16 + sub];
        a0 += __uint_as_float(u0.x << 16);
        a1 += __uint_as_float(u0.x & 0xffff0000u);
        a2 += __uint_as_float(u0.y << 16);
        a3 += __uint_as_float(u0.y & 0xffff0000u);
        a4 += __uint_as_float(u0.z << 16);
        a5 += __uint_as_float(u0.z & 0xffff0000u);
        a6 += __uint_as_float(u0.w << 16);
        a7 += __uint_as_float(u0.w & 0xffff0000u);
    }
    const float4* b4 = (const float4*)(bias + sub * 8);
    float4 bb0 = b4[0], bb1 = b4[1];
    float4 r0, r1;
    r0.x = fmaxf(fmaf(a0, di, bb0.x), 0.f);
    r0.y = fmaxf(fmaf(a1, di, bb0.y), 0.f);
    r0.z = fmaxf(fmaf(a2, di, bb0.z), 0.f);
    r0.w = fmaxf(fmaf(a3, di, bb0.w), 0.f);
    r1.x = fmaxf(fmaf(a4, di, bb1.x), 0.f);
    r1.y = fmaxf(fmaf(a5, di, bb1.y), 0.f);
    r1.z = fmaxf(fmaf(a6, di, bb1.z), 0.f);
    r1.w = fmaxf(fmaf(a7, di, bb1.w), 0.f);
    float4* o = (float4*)(h2 + (size_t)i * 128 + sub * 8);
    o[0] = r0; o[1] = r1;
}

__device__ inline int lbound(const int* __restrict__ a, int n, int key) {
    int lo = 0, hi = n;
    while (lo < hi) {
        int mid = (lo + hi) >> 1;
        if (a[mid] < key) lo = mid + 1;
        else hi = mid;
    }
    return lo;
}

// ---------------- K6: group mean-pool partial sums (16 chunks/group) -------
__global__ __launch_bounds__(128) void k_pool(const float* __restrict__ h2,
                                              const int* __restrict__ batch,
                                              float* __restrict__ gsum) {
    int g = blockIdx.x >> 4, chunk = blockIdx.x & 15;
    int lo = lbound(batch, NN, g);
    int hi = lbound(batch, NN, g + 1);
    int cnt = hi - lo;
    int per = (cnt + 15) >> 4;
    int rs = lo + chunk * per;
    int re = rs + per;
    if (re > hi) re = hi;
    if (rs >= re) return;
    float s = 0.f;
    int f = threadIdx.x;
    for (int r = rs; r < re; ++r) s += h2[(size_t)r * 128 + f];
    atomicAdd(&gsum[g * 128 + f], s);
}

// ---------------- K7: head (mean, fc1 + relu, actor softmax, critic) -------
__global__ __launch_bounds__(64) void k_head(const float* __restrict__ gsum,
                                             const int* __restrict__ batch,
                                             const float* __restrict__ fc1_w,
                                             const float* __restrict__ fc1_b,
                                             const float* __restrict__ actor_w,
                                             const float* __restrict__ actor_b,
                                             const float* __restrict__ critic_w,
                                             const float* __restrict__ critic_b,
                                             float* __restrict__ out) {
    __shared__ float gs[128];
    __shared__ float zs[64];
    __shared__ float ls[8], es[8];
    int g = blockIdx.x, t = threadIdx.x;
    int lo = lbound(batch, NN, g), hi = lbound(batch, NN, g + 1);
    float invc = 1.f / fmaxf((float)(hi - lo), 1.f);
    gs[t] = gsum[g * 128 + t] * invc;
    gs[t + 64] = gsum[g * 128 + 64 + t] * invc;
    __syncthreads();
    float z = fc1_b[t];
    for (int k = 0; k < 128; k++) z = fmaf(gs[k], fc1_w[k * 64 + t], z);
    zs[t] = fmaxf(z, 0.f);
    __syncthreads();
    if (t < 8) {
        float l = actor_b[t];
        for (int k = 0; k < 64; k++) l = fmaf(zs[k], actor_w[k * 8 + t], l);
        ls[t] = l;
    }
    __syncthreads();
    if (t < 8) {
        float m = ls[0];
#pragma unroll
        for (int j = 1; j < 8; j++) m = fmaxf(m, ls[j]);
        es[t] = expf(ls[t] - m);
    }
    __syncthreads();
    if (t < 8) {
        float ssum = 0.f;
#pragma unroll
        for (int j = 0; j < 8; j++) ssum += es[j];
        out[g * 8 + t] = es[t] / ssum;
    }
    if (t == 32) {
        float v = critic_b[0];
        for (int k = 0; k < 64; k++) v = fmaf(zs[k], critic_w[k], v);
        out[GG * TT + g] = v;
    }
}

extern "C" void kernel_launch(void* const* d_in, const int* in_sizes, int n_in,
                              void* d_out, int out_size, void* d_ws, size_t ws_size,
                              hipStream_t stream) {
    const float* x        = (const float*)d_in[0];
    const int*   ei       = (const int*)d_in[1];
    const int*   batch    = (const int*)d_in[2];
    const float* W        = (const float*)d_in[3];
    const float* b        = (const float*)d_in[4];
    const float* fc1_w    = (const float*)d_in[5];
    const float* fc1_b    = (const float*)d_in[6];
    const float* actor_w  = (const float*)d_in[7];
    const float* actor_b  = (const float*)d_in[8];
    const float* critic_w = (const float*)d_in[9];
    const float* critic_b = (const float*)d_in[10];
    float* out = (float*)d_out;

    char* ws = (char*)d_ws;
    size_t off = 0;
    unsigned* hs     = (unsigned*)(ws + off); off += (size_t)NN * 64 * 4;  // 12.8 MB
    float* h2        = (float*)(ws + off);    off += (size_t)NN * HH * 4;  // 25.6 MB
    float* dinv      = (float*)(ws + off);    off += (size_t)NN * 4;
    int*   deg       = (int*)(ws + off);      off += (size_t)NN * 4;
    int*   row_ptr   = (int*)(ws + off);      off += (size_t)(NN + 1) * 4 + 12;
    int*   srcs      = (int*)(ws + off);      off += (size_t)EE * 4;       // 3.2 MB
    unsigned* etmp   = (unsigned*)(ws + off); off += (size_t)EE * 4;       // 3.2 MB
    int*   table     = (int*)(ws + off);      off += (size_t)NSB * NB * 4;
    int*   bbase     = (int*)(ws + off);      off += (size_t)(NB + 1) * 4;
    float* gsum      = (float*)(ws + off);    off += (size_t)GG * HH * 4;

    hipMemsetAsync(gsum, 0, (size_t)GG * HH * 4, stream);

    const int* src = ei;        // edge_index[0]
    const int* dst = ei + EE;   // edge_index[1]

    kb1<<<NSB, 1024, 0, stream>>>(dst, table);
    kb2<<<1, 256, 0, stream>>>(table, bbase);
    kb3<<<NSB, 1024, 0, stream>>>(src, dst, table, etmp);
    kdeg<<<NB, 256, 0, stream>>>(etmp, bbase, deg);
    k_rowptr<<<NB, 256, 0, stream>>>(deg, bbase, row_ptr, dinv);
    k_filll<<<NB, 256, 0, stream>>>(etmp, bbase, row_ptr, srcs);
    k_gemm<<<(NN + 63) / 64, 256, 0, stream>>>(x, W, dinv, hs);
    k_aggr<<<NN / 16, 256, 0, stream>>>((const uint4*)hs, row_ptr, srcs, dinv, b, h2);
    k_pool<<<GG * 16, 128, 0, stream>>>(h2, batch, gsum);
    k_head<<<GG, 64, 0, stream>>>(gsum, batch, fc1_w, fc1_b, actor_w, actor_b,
                                  critic_w, critic_b, out);
}

// Round 6
// 221.233 us; speedup vs baseline: 1.8410x; 1.0264x over previous
//
#include <hip/hip_runtime.h>
#include <hip/hip_bf16.h>

#define NN 50000
#define EE 800000
#define FF 128
#define HH 128
#define HID2 64
#define TT 8
#define GG 64
#define NB 196          // buckets of 256 dst nodes (NN < 196*256; NN < 2^16)
#define NSB 256         // scatter blocks
#define EPB (EE / NSB)  // 3125 edges per scatter block

__device__ inline unsigned short f2bf(float f) {
    union { float f; unsigned u; } v; v.f = f;
    unsigned r = v.u + 0x7fff + ((v.u >> 16) & 1);  // RNE
    return (unsigned short)(r >> 16);
}

// ---- KB1: per-(scatter-block, bucket) edge counts (LDS hist) --------------
__global__ __launch_bounds__(256) void kb1(const int* __restrict__ dst,
                                           int* __restrict__ table) {
    __shared__ int cnt[NB];
    int t = threadIdx.x, blk = blockIdx.x;
    for (int i = t; i < NB; i += 256) cnt[i] = 0;
    __syncthreads();
    int e0 = blk * EPB;
    for (int e = e0 + t; e < e0 + EPB; e += 256)
        atomicAdd(&cnt[dst[e] >> 8], 1);
    __syncthreads();
    for (int i = t; i < NB; i += 256) table[blk * NB + i] = cnt[i];
}

// ---- KB2: exact scan of table -> scatter offsets; bucket bases ------------
__global__ __launch_bounds__(256) void kb2(int* __restrict__ table,
                                           int* __restrict__ bbase) {
    __shared__ int s[256];
    int b = threadIdx.x;
    int tot = 0;
    if (b < NB)
        for (int blk = 0; blk < NSB; blk++) tot += table[blk * NB + b];
    s[b] = (b < NB) ? tot : 0;
    __syncthreads();
    for (int off = 1; off < 256; off <<= 1) {
        int a = s[b];
        int w = (b >= off) ? s[b - off] : 0;
        __syncthreads();
        s[b] = a + w;
        __syncthreads();
    }
    int base = (b == 0) ? 0 : s[b - 1];
    if (b < NB) {
        bbase[b] = base;
        int run = base;
        for (int blk = 0; blk < NSB; blk++) {
            int v = table[blk * NB + b];
            table[blk * NB + b] = run;
            run += v;
        }
    }
    if (b == 0) bbase[NB] = EE;
}

// ---- KB3: scatter edges into bucket order (packed dst<<16|src) ------------
// (blk,bucket) output runs are private -> no inter-XCD line ping-pong.
__global__ __launch_bounds__(256) void kb3(const int* __restrict__ src,
                                           const int* __restrict__ dst,
                                           const int* __restrict__ table,
                                           unsigned* __restrict__ etmp) {
    __shared__ int ofs[NB];
    __shared__ int cur[NB];
    int t = threadIdx.x, blk = blockIdx.x;
    for (int i = t; i < NB; i += 256) { ofs[i] = table[blk * NB + i]; cur[i] = 0; }
    __syncthreads();
    int e0 = blk * EPB;
    for (int e = e0 + t; e < e0 + EPB; e += 256) {
        int d = dst[e];
        int b = d >> 8;
        int r = atomicAdd(&cur[b], 1);
        etmp[ofs[b] + r] = ((unsigned)d << 16) | (unsigned)src[e];
    }
}

// ---- K_CSR: per-bucket  hist -> scan -> row_ptr/dinv -> CSR fill ----------
__global__ __launch_bounds__(256) void k_csr(const unsigned* __restrict__ etmp,
                                             const int* __restrict__ bbase,
                                             int* __restrict__ row_ptr,
                                             float* __restrict__ dinv,
                                             int* __restrict__ srcs) {
    __shared__ int s[256];
    __shared__ int cur[256];
    int t = threadIdx.x, b = blockIdx.x;
    s[t] = 0;
    __syncthreads();
    int e0 = bbase[b], e1 = bbase[b + 1];
    for (int e = e0 + t; e < e1; e += 256)
        atomicAdd(&s[(etmp[e] >> 16) & 255], 1);
    __syncthreads();
    int v = s[t];
    // inclusive scan of s
    for (int off = 1; off < 256; off <<= 1) {
        int a = s[t];
        int w = (t >= off) ? s[t - off] : 0;
        __syncthreads();
        s[t] = a + w;
        __syncthreads();
    }
    int excl = s[t] - v + e0;   // e0 == bbase[b] == row_ptr[b*256]
    int node = b * 256 + t;
    if (node < NN) {
        row_ptr[node] = excl;
        dinv[node] = rsqrtf((float)(v + 1));  // +1 self-loop
    }
    if (b == NB - 1 && t == 0) row_ptr[NN] = EE;
    cur[t] = excl;
    __syncthreads();
    for (int e = e0 + t; e < e1; e += 256) {
        unsigned u = etmp[e];
        int slot = atomicAdd(&cur[(u >> 16) & 255], 1);
        srcs[slot] = (int)(u & 0xffffu);
    }
}

// ---------------- K4: hs = bf16( (x @ W) * dinv[row] )  --------------------
__global__ __launch_bounds__(256) void k_gemm(const float* __restrict__ x,
                                              const float* __restrict__ W,
                                              const float* __restrict__ dinv,
                                              unsigned* __restrict__ hs) {
    __shared__ float xs[64 * 36];
    __shared__ float ws[32 * 132];
    int tid = threadIdx.x;
    int tx = tid & 15, ty = tid >> 4;
    int r0 = blockIdx.x * 64;
    float acc[4][8];
#pragma unroll
    for (int r = 0; r < 4; r++)
#pragma unroll
        for (int c = 0; c < 8; c++) acc[r][c] = 0.f;

    for (int k0 = 0; k0 < 128; k0 += 32) {
        {
            int row = tid >> 2, q = tid & 3;
            int gr = r0 + row;
            float4 a0 = {0, 0, 0, 0}, a1 = {0, 0, 0, 0};
            if (gr < NN) {
                const float4* p = (const float4*)(x + (size_t)gr * 128 + k0 + q * 8);
                a0 = p[0]; a1 = p[1];
            }
            float* dp = &xs[row * 36 + q * 8];
            ((float4*)dp)[0] = a0; ((float4*)dp)[1] = a1;
        }
        {
            int kr = tid >> 3, q = tid & 7;
            const float4* p = (const float4*)(W + (size_t)(k0 + kr) * 128 + q * 16);
            float4 b0 = p[0], b1 = p[1], b2 = p[2], b3 = p[3];
            float* dp = &ws[kr * 132 + q * 16];
            ((float4*)dp)[0] = b0; ((float4*)dp)[1] = b1;
            ((float4*)dp)[2] = b2; ((float4*)dp)[3] = b3;
        }
        __syncthreads();
#pragma unroll
        for (int kk = 0; kk < 32; kk++) {
            float a[4];
#pragma unroll
            for (int r = 0; r < 4; r++) a[r] = xs[(ty * 4 + r) * 36 + kk];
            float4 b0 = *(const float4*)&ws[kk * 132 + tx * 8];
            float4 b1 = *(const float4*)&ws[kk * 132 + tx * 8 + 4];
            float bv[8] = {b0.x, b0.y, b0.z, b0.w, b1.x, b1.y, b1.z, b1.w};
#pragma unroll
            for (int r = 0; r < 4; r++)
#pragma unroll
                for (int c = 0; c < 8; c++)
                    acc[r][c] = fmaf(a[r], bv[c], acc[r][c]);
        }
        __syncthreads();
    }
#pragma unroll
    for (int r = 0; r < 4; r++) {
        int gr = r0 + ty * 4 + r;
        if (gr < NN) {
            float di = dinv[gr];
            unsigned p0 = f2bf(acc[r][0] * di) | ((unsigned)f2bf(acc[r][1] * di) << 16);
            unsigned p1 = f2bf(acc[r][2] * di) | ((unsigned)f2bf(acc[r][3] * di) << 16);
            unsigned p2 = f2bf(acc[r][4] * di) | ((unsigned)f2bf(acc[r][5] * di) << 16);
            unsigned p3 = f2bf(acc[r][6] * di) | ((unsigned)f2bf(acc[r][7] * di) << 16);
            uint4 o = {p0, p1, p2, p3};
            *(uint4*)(hs + (size_t)gr * 64 + tx * 4) = o;
        }
    }
}

// ---------------- K5: gather + bias + relu + fused hierarchical pool -------
// Block = 256 threads = 16 quarter-waves; each qwave handles 2 consecutive
// nodes (block covers 32 nodes). Per-qwave register accumulator, flushed on
// group change into LDS group slots; one global-atomic flush per block.
__global__ __launch_bounds__(256) void k_aggr(const uint4* __restrict__ hs4,
                                              const int* __restrict__ row_ptr,
                                              const int* __restrict__ srcs,
                                              const float* __restrict__ dinv,
                                              const float* __restrict__ bias,
                                              const int* __restrict__ batch,
                                              float* __restrict__ gsum) {
    __shared__ float gacc[GG * 128];   // up to 64 group slots (worst-case span)
    int tid = threadIdx.x;
    int qid = tid >> 4, sub = tid & 15;
    int i_base = blockIdx.x * 32;
    int g_first = batch[i_base];
    int last = i_base + 31; if (last >= NN) last = NN - 1;
    int gspan = batch[last] - g_first + 1;
    for (int idx = tid; idx < gspan * 128; idx += 256) gacc[idx] = 0.f;
    __syncthreads();

    const float4* b4 = (const float4*)(bias + sub * 8);
    float4 bb0 = b4[0], bb1 = b4[1];

    float racc[8];
#pragma unroll
    for (int j = 0; j < 8; j++) racc[j] = 0.f;
    int cur_lg = -1;

    for (int n = 0; n < 2; n++) {
        int i = i_base + qid * 2 + n;
        if (i >= NN) break;
        int lg = batch[i] - g_first;
        if (lg != cur_lg) {
            if (cur_lg >= 0) {
                float* gp = &gacc[cur_lg * 128 + sub * 8];
#pragma unroll
                for (int j = 0; j < 8; j++) atomicAdd(&gp[j], racc[j]);
#pragma unroll
                for (int j = 0; j < 8; j++) racc[j] = 0.f;
            }
            cur_lg = lg;
        }
        float di = dinv[i];
        uint4 su = hs4[(size_t)i * 16 + sub];
        float a0 = __uint_as_float(su.x << 16);
        float a1 = __uint_as_float(su.x & 0xffff0000u);
        float a2 = __uint_as_float(su.y << 16);
        float a3 = __uint_as_float(su.y & 0xffff0000u);
        float a4 = __uint_as_float(su.z << 16);
        float a5 = __uint_as_float(su.z & 0xffff0000u);
        float a6 = __uint_as_float(su.w << 16);
        float a7 = __uint_as_float(su.w & 0xffff0000u);
        int e = row_ptr[i], e1 = row_ptr[i + 1];
        for (; e + 3 < e1; e += 4) {
            int s0 = srcs[e], s1 = srcs[e + 1], s2 = srcs[e + 2], s3 = srcs[e + 3];
            uint4 u0 = hs4[(size_t)s0 * 16 + sub];
            uint4 u1 = hs4[(size_t)s1 * 16 + sub];
            uint4 u2 = hs4[(size_t)s2 * 16 + sub];
            uint4 u3 = hs4[(size_t)s3 * 16 + sub];
            a0 += __uint_as_float(u0.x << 16); a1 += __uint_as_float(u0.x & 0xffff0000u);
            a2 += __uint_as_float(u0.y << 16); a3 += __uint_as_float(u0.y & 0xffff0000u);
            a4 += __uint_as_float(u0.z << 16); a5 += __uint_as_float(u0.z & 0xffff0000u);
            a6 += __uint_as_float(u0.w << 16); a7 += __uint_as_float(u0.w & 0xffff0000u);
            a0 += __uint_as_float(u1.x << 16); a1 += __uint_as_float(u1.x & 0xffff0000u);
            a2 += __uint_as_float(u1.y << 16); a3 += __uint_as_float(u1.y & 0xffff0000u);
            a4 += __uint_as_float(u1.z << 16); a5 += __uint_as_float(u1.z & 0xffff0000u);
            a6 += __uint_as_float(u1.w << 16); a7 += __uint_as_float(u1.w & 0xffff0000u);
            a0 += __uint_as_float(u2.x << 16); a1 += __uint_as_float(u2.x & 0xffff0000u);
            a2 += __uint_as_float(u2.y << 16); a3 += __uint_as_float(u2.y & 0xffff0000u);
            a4 += __uint_as_float(u2.z << 16); a5 += __uint_as_float(u2.z & 0xffff0000u);
            a6 += __uint_as_float(u2.w << 16); a7 += __uint_as_float(u2.w & 0xffff0000u);
            a0 += __uint_as_float(u3.x << 16); a1 += __uint_as_float(u3.x & 0xffff0000u);
            a2 += __uint_as_float(u3.y << 16); a3 += __uint_as_float(u3.y & 0xffff0000u);
            a4 += __uint_as_float(u3.z << 16); a5 += __uint_as_float(u3.z & 0xffff0000u);
            a6 += __uint_as_float(u3.w << 16); a7 += __uint_as_float(u3.w & 0xffff0000u);
        }
        for (; e < e1; ++e) {
            uint4 u0 = hs4[(size_t)srcs[e] * 16 + sub];
            a0 += __uint_as_float(u0.x << 16); a1 += __uint_as_float(u0.x & 0xffff0000u);
            a2 += __uint_as_float(u0.y << 16); a3 += __uint_as_float(u0.y & 0xffff0000u);
            a4 += __uint_as_float(u0.z << 16); a5 += __uint_as_float(u0.z & 0xffff0000u);
            a6 += __uint_as_float(u0.w << 16); a7 += __uint_as_float(u0.w & 0xffff0000u);
        }
        racc[0] += fmaxf(fmaf(a0, di, bb0.x), 0.f);
        racc[1] += fmaxf(fmaf(a1, di, bb0.y), 0.f);
        racc[2] += fmaxf(fmaf(a2, di, bb0.z), 0.f);
        racc[3] += fmaxf(fmaf(a3, di, bb0.w), 0.f);
        racc[4] += fmaxf(fmaf(a4, di, bb1.x), 0.f);
        racc[5] += fmaxf(fmaf(a5, di, bb1.y), 0.f);
        racc[6] += fmaxf(fmaf(a6, di, bb1.z), 0.f);
        racc[7] += fmaxf(fmaf(a7, di, bb1.w), 0.f);
    }
    if (cur_lg >= 0) {
        float* gp = &gacc[cur_lg * 128 + sub * 8];
#pragma unroll
        for (int j = 0; j < 8; j++) atomicAdd(&gp[j], racc[j]);
    }
    __syncthreads();
    for (int idx = tid; idx < gspan * 128; idx += 256) {
        float v = gacc[idx];
        if (v != 0.f)
            atomicAdd(&gsum[(g_first + (idx >> 7)) * 128 + (idx & 127)], v);
    }
}

__device__ inline int lbound(const int* __restrict__ a, int n, int key) {
    int lo = 0, hi = n;
    while (lo < hi) {
        int mid = (lo + hi) >> 1;
        if (a[mid] < key) lo = mid + 1;
        else hi = mid;
    }
    return lo;
}

// ---------------- K7: head (mean, fc1 + relu, actor softmax, critic) -------
__global__ __launch_bounds__(64) void k_head(const float* __restrict__ gsum,
                                             const int* __restrict__ batch,
                                             const float* __restrict__ fc1_w,
                                             const float* __restrict__ fc1_b,
                                             const float* __restrict__ actor_w,
                                             const float* __restrict__ actor_b,
                                             const float* __restrict__ critic_w,
                                             const float* __restrict__ critic_b,
                                             float* __restrict__ out) {
    __shared__ float gs[128];
    __shared__ float zs[64];
    __shared__ float ls[8], es[8];
    int g = blockIdx.x, t = threadIdx.x;
    int lo = lbound(batch, NN, g), hi = lbound(batch, NN, g + 1);
    float invc = 1.f / fmaxf((float)(hi - lo), 1.f);
    gs[t] = gsum[g * 128 + t] * invc;
    gs[t + 64] = gsum[g * 128 + 64 + t] * invc;
    __syncthreads();
    float z = fc1_b[t];
    for (int k = 0; k < 128; k++) z = fmaf(gs[k], fc1_w[k * 64 + t], z);
    zs[t] = fmaxf(z, 0.f);
    __syncthreads();
    if (t < 8) {
        float l = actor_b[t];
        for (int k = 0; k < 64; k++) l = fmaf(zs[k], actor_w[k * 8 + t], l);
        ls[t] = l;
    }
    __syncthreads();
    if (t < 8) {
        float m = ls[0];
#pragma unroll
        for (int j = 1; j < 8; j++) m = fmaxf(m, ls[j]);
        es[t] = expf(ls[t] - m);
    }
    __syncthreads();
    if (t < 8) {
        float ssum = 0.f;
#pragma unroll
        for (int j = 0; j < 8; j++) ssum += es[j];
        out[g * 8 + t] = es[t] / ssum;
    }
    if (t == 32) {
        float v = critic_b[0];
        for (int k = 0; k < 64; k++) v = fmaf(zs[k], critic_w[k], v);
        out[GG * TT + g] = v;
    }
}

extern "C" void kernel_launch(void* const* d_in, const int* in_sizes, int n_in,
                              void* d_out, int out_size, void* d_ws, size_t ws_size,
                              hipStream_t stream) {
    const float* x        = (const float*)d_in[0];
    const int*   ei       = (const int*)d_in[1];
    const int*   batch    = (const int*)d_in[2];
    const float* W        = (const float*)d_in[3];
    const float* b        = (const float*)d_in[4];
    const float* fc1_w    = (const float*)d_in[5];
    const float* fc1_b    = (const float*)d_in[6];
    const float* actor_w  = (const float*)d_in[7];
    const float* actor_b  = (const float*)d_in[8];
    const float* critic_w = (const float*)d_in[9];
    const float* critic_b = (const float*)d_in[10];
    float* out = (float*)d_out;

    char* ws = (char*)d_ws;
    size_t off = 0;
    unsigned* hs     = (unsigned*)(ws + off); off += (size_t)NN * 64 * 4;  // 12.8 MB
    float* dinv      = (float*)(ws + off);    off += (size_t)NN * 4;
    int*   row_ptr   = (int*)(ws + off);      off += (size_t)(NN + 1) * 4 + 12;
    int*   srcs      = (int*)(ws + off);      off += (size_t)EE * 4;       // 3.2 MB
    unsigned* etmp   = (unsigned*)(ws + off); off += (size_t)EE * 4;       // 3.2 MB
    int*   table     = (int*)(ws + off);      off += (size_t)NSB * NB * 4; // 200 KB
    int*   bbase     = (int*)(ws + off);      off += (size_t)(NB + 1) * 4;
    float* gsum      = (float*)(ws + off);    off += (size_t)GG * HH * 4;

    hipMemsetAsync(gsum, 0, (size_t)GG * HH * 4, stream);

    const int* src = ei;        // edge_index[0]
    const int* dst = ei + EE;   // edge_index[1]

    kb1<<<NSB, 256, 0, stream>>>(dst, table);
    kb2<<<1, 256, 0, stream>>>(table, bbase);
    kb3<<<NSB, 256, 0, stream>>>(src, dst, table, etmp);
    k_csr<<<NB, 256, 0, stream>>>(etmp, bbase, row_ptr, dinv, srcs);
    k_gemm<<<(NN + 63) / 64, 256, 0, stream>>>(x, W, dinv, hs);
    k_aggr<<<(NN + 31) / 32, 256, 0, stream>>>((const uint4*)hs, row_ptr, srcs,
                                               dinv, b, batch, gsum);
    k_head<<<GG, 64, 0, stream>>>(gsum, batch, fc1_w, fc1_b, actor_w, actor_b,
                                  critic_w, critic_b, out);
}